// Round 2
// baseline (322.320 us; speedup 1.0000x reference)
//
#include <hip/hip_runtime.h>
#include <hip/hip_cooperative_groups.h>
#include <cfloat>
#include <climits>
#include <math.h>

namespace cg = cooperative_groups;

#define NSTREAM 4
#define NCLS    20
#define NGT     (NSTREAM * NCLS)     // 80
#define XBLK    128                  // x-blocks per stream in phase A
#define GRID    (XBLK * NSTREAM)     // 512 blocks (2/CU -> trivially co-resident)
#define TPB     256

// Workspace layout (float offsets):
//   pv    [80][128]  @ 0
//   pi    [80][128]  @ 10240   (int)
//   gtb   [80][4]    @ 20480
//   gts   [80]       @ 20800
//   valid [80]       @ 20880   (int)
//   sums  [80]       @ 20960
//   cnts  [80]       @ 21040
//   neg   [1]        @ 21120
//   nv    [1]        @ 21121   (int)
//   glist [80]       @ 21122   (int)

__global__ __launch_bounds__(TPB) void fused_kernel(
    const float* __restrict__ rois,
    const float* __restrict__ c0, const float* __restrict__ c1,
    const float* __restrict__ c2, const float* __restrict__ c3,
    const float* __restrict__ clsnew,
    const int* __restrict__ imlab,
    float* ws, float* __restrict__ d_out, int R)
{
    cg::grid_group grid = cg::this_grid();

    float* pv    = ws;
    int*   pi    = (int*)(ws + 10240);
    float* gtb   = ws + 20480;
    float* gts   = ws + 20800;
    int*   valid = (int*)(ws + 20880);
    float* sums  = ws + 20960;
    float* cnts  = ws + 21040;
    float* negp  = ws + 21120;
    int*   nvp   = (int*)(ws + 21121);
    int*   glist = (int*)(ws + 21122);

    const int bid  = blockIdx.x;
    const int tid  = threadIdx.x;
    const int lane = tid & 63;
    const int wv   = tid >> 6;

    __shared__ float sv[NCLS][4];
    __shared__ int   si[NCLS][4];
    __shared__ float s_box[NGT][4];
    __shared__ float4 s_gt[NGT];
    __shared__ float  s_ga[NGT];
    __shared__ float  s_gs[NGT];
    __shared__ int    s_lab[NGT];
    __shared__ int    s_gidx[NGT];
    __shared__ float  s_sum[NGT];
    __shared__ float  s_cnt[NGT];
    __shared__ float  s_neg;
    __shared__ float  s_wred[4];

    // ---------------- Phase A: per-(stream,class) argmax partials ----------
    {
        const int s  = bid >> 7;          // stream
        const int xb = bid & (XBLK - 1);  // x-block within stream
        const float* cls = (s == 0) ? c0 : (s == 1) ? c1 : (s == 2) ? c2 : c3;

        float bv[NCLS];
        int   bi_[NCLS];
#pragma unroll
        for (int c = 0; c < NCLS; ++c) { bv[c] = -FLT_MAX; bi_[c] = 0; }

        const int gid = xb * TPB + tid;
        const int stride = XBLK * TPB;
        for (int r = gid; r < R; r += stride) {
            const float4* row = reinterpret_cast<const float4*>(cls + (size_t)r * NCLS);
#pragma unroll
            for (int q = 0; q < NCLS / 4; ++q) {
                float4 v = row[q];
                float vals[4] = { v.x, v.y, v.z, v.w };
#pragma unroll
                for (int k = 0; k < 4; ++k) {
                    const int c = q * 4 + k;
                    if (vals[k] > bv[c]) { bv[c] = vals[k]; bi_[c] = r; }
                }
            }
        }
        // wave-level shuffle reduction (first-occurrence tie-break)
#pragma unroll
        for (int off = 32; off > 0; off >>= 1) {
#pragma unroll
            for (int c = 0; c < NCLS; ++c) {
                float ov = __shfl_down(bv[c], off);
                int   oi = __shfl_down(bi_[c], off);
                if (ov > bv[c] || (ov == bv[c] && oi < bi_[c])) { bv[c] = ov; bi_[c] = oi; }
            }
        }
        if (lane == 0) {
#pragma unroll
            for (int c = 0; c < NCLS; ++c) { sv[c][wv] = bv[c]; si[c][wv] = bi_[c]; }
        }
        __syncthreads();
        if (tid < NCLS) {
            float best = sv[tid][0]; int bidx = si[tid][0];
#pragma unroll
            for (int w = 1; w < 4; ++w) {
                float v = sv[tid][w]; int i = si[tid][w];
                if (v > best || (v == best && i < bidx)) { best = v; bidx = i; }
            }
            const int p = s * NCLS + tid;
            pv[(size_t)p * XBLK + xb] = best;
            pi[(size_t)p * XBLK + xb] = bidx;
        }
    }

    grid.sync();

    // ---------------- Phase B: final argmax + instance selector (block 0) --
    if (bid == 0) {
        if (tid < NGT) {
            const int st = tid / NCLS;
            const int c  = tid % NCLS;
            const float* v  = pv + (size_t)tid * XBLK;
            const int*   ii = pi + (size_t)tid * XBLK;
            float best = -FLT_MAX; int bidx = INT_MAX;
            for (int b = 0; b < XBLK; ++b) {
                float val = v[b]; int idx = ii[b];
                if (val > best || (val == best && idx < bidx)) { best = val; bidx = idx; }
            }
            const int g = c * NSTREAM + st;    // class-major gt index
            float4 box = reinterpret_cast<const float4*>(rois)[bidx];
            s_box[g][0] = box.x; s_box[g][1] = box.y;
            s_box[g][2] = box.z; s_box[g][3] = box.w;
            gtb[g * 4 + 0] = box.x; gtb[g * 4 + 1] = box.y;
            gtb[g * 4 + 2] = box.z; gtb[g * 4 + 3] = box.w;
            gts[g] = best;
            d_out[1 + g * 4 + 0] = box.x; d_out[1 + g * 4 + 1] = box.y;
            d_out[1 + g * 4 + 2] = box.z; d_out[1 + g * 4 + 3] = box.w;
            d_out[1 + NGT * 4 + g] = best;
            sums[g] = 0.0f; cnts[g] = 0.0f;
        }
        if (tid == 0) negp[0] = 0.0f;
        __syncthreads();

        if (tid < NCLS) {
            const int c = tid;
            const bool present = imlab[c] > 0;
            float bx[NSTREAM][4], area[NSTREAM];
#pragma unroll
            for (int s = 0; s < NSTREAM; ++s) {
#pragma unroll
                for (int k = 0; k < 4; ++k) bx[s][k] = s_box[c * NSTREAM + s][k];
                area[s] = (bx[s][2] - bx[s][0] + 1.0f) * (bx[s][3] - bx[s][1] + 1.0f);
            }
            bool active[NSTREAM], sel[NSTREAM];
#pragma unroll
            for (int s = 0; s < NSTREAM; ++s) { active[s] = present; sel[s] = false; }

            for (int it = 0; it < NSTREAM; ++it) {
                int m = 0; float best = -FLT_MAX;
#pragma unroll
                for (int s = 0; s < NSTREAM; ++s) {
                    float v = active[s] ? area[s] : -FLT_MAX;
                    if (v > best) { best = v; m = s; }
                }
                const float bmx1 = bx[m][0], bmy1 = bx[m][1];
                const float bmx2 = bx[m][2], bmy2 = bx[m][3];
                const float am = area[m];
                bool nact[NSTREAM];
#pragma unroll
                for (int s = 0; s < NSTREAM; ++s) {
                    float x1 = fmaxf(bx[s][0], bmx1), y1 = fmaxf(bx[s][1], bmy1);
                    float x2 = fminf(bx[s][2], bmx2), y2 = fminf(bx[s][3], bmy2);
                    float iw = fmaxf(x2 - x1 + 1.0f, 0.0f), ih = fmaxf(y2 - y1 + 1.0f, 0.0f);
                    float inter = iw * ih;
                    float iou = inter / (area[s] + am - inter);
                    bool enclosed = (bx[s][0] > bmx1) && (bx[s][1] > bmy1) &&
                                    (bx[s][2] < bmx2) && (bx[s][3] < bmy2);
                    bool pick = active[s] && (s == m);
                    bool keep = active[s] && (iou < 0.1f) && (!enclosed);
                    sel[s] = sel[s] || pick || keep;
                    nact[s] = active[s] && !((iou > 0.3f) || enclosed || keep);
                }
#pragma unroll
                for (int s = 0; s < NSTREAM; ++s) active[s] = nact[s];
            }
#pragma unroll
            for (int s = 0; s < NSTREAM; ++s) {
                const int g = c * NSTREAM + s;
                valid[g] = sel[s] ? 1 : 0;
                d_out[1 + NGT * 4 + NGT + g] = sel[s] ? 1.0f : 0.0f;
            }
        }
        __syncthreads();

        if (tid == 0) {   // compact valid gt list (ascending g preserves tie-break)
            int nv = 0;
            for (int g = 0; g < NGT; ++g) if (valid[g]) glist[nv++] = g;
            nvp[0] = nv;
        }
    }

    grid.sync();

    // ---------------- Phase C: roi -> gt assignment + bin accumulation -----
    {
        const int nv = nvp[0];
        if (tid < nv) {
            const int g = glist[tid];
            float4 b = reinterpret_cast<const float4*>(gtb)[g];
            s_gt[tid] = b;
            s_ga[tid] = (b.z - b.x + 1.0f) * (b.w - b.y + 1.0f);
            s_gs[tid] = gts[g];
            s_lab[tid] = g / NSTREAM + 1;
            s_gidx[tid] = g;
        }
        if (tid < NGT) { s_sum[tid] = 0.0f; s_cnt[tid] = 0.0f; }
        if (tid == 0) s_neg = 0.0f;
        __syncthreads();

        for (int r = bid * TPB + tid; r < R; r += GRID * TPB) {
            float4 bb = reinterpret_cast<const float4*>(rois)[r];
            float ab = (bb.z - bb.x + 1.0f) * (bb.w - bb.y + 1.0f);
            float best = -FLT_MAX; int bestj = 0;
            for (int j = 0; j < nv; ++j) {
                float4 gt = s_gt[j];
                float x1 = fmaxf(bb.x, gt.x), y1 = fmaxf(bb.y, gt.y);
                float x2 = fminf(bb.z, gt.z), y2 = fminf(bb.w, gt.w);
                float iw = fmaxf(x2 - x1 + 1.0f, 0.0f), ih = fmaxf(y2 - y1 + 1.0f, 0.0f);
                float inter = iw * ih;
                float v = inter / (ab + s_ga[j] - inter);
                if (v > best) { best = v; bestj = j; }  // first-max tie-break
            }
            if (nv > 0) {
                if (best >= 0.5f) {                     // fg
                    const int lab = s_lab[bestj];
                    float pa = clsnew[(size_t)r * (NCLS + 1) + lab];
                    pa = fminf(fmaxf(pa, 1e-9f), 1.0f - 1e-9f);
                    atomicAdd(&s_sum[bestj], pa);
                    atomicAdd(&s_cnt[bestj], 1.0f);
                } else if (best >= 0.1f) {              // bg with nonzero weight
                    float p0 = clsnew[(size_t)r * (NCLS + 1)];
                    p0 = fminf(fmaxf(p0, 1e-9f), 1.0f - 1e-9f);
                    atomicAdd(&s_neg, logf(p0) * s_gs[bestj]);
                }
            }
        }
        __syncthreads();

        if (tid < nv && s_cnt[tid] != 0.0f) {
            atomicAdd(&sums[s_gidx[tid]], s_sum[tid]);
            atomicAdd(&cnts[s_gidx[tid]], s_cnt[tid]);
        }
        if (tid == 0 && s_neg != 0.0f) atomicAdd(negp, s_neg);
    }

    grid.sync();

    // ---------------- Phase D: finalize loss (block 0) ---------------------
    if (bid == 0) {
        float t = 0.0f;
        if (tid < NGT) {
            float cnt = cnts[tid];
            if (valid[tid] && cnt > 0.0f)
                t = logf(sums[tid] / cnt) * cnt * gts[tid];
        }
#pragma unroll
        for (int off = 32; off > 0; off >>= 1) t += __shfl_down(t, off);
        if (lane == 0) s_wred[wv] = t;
        __syncthreads();
        if (tid == 0) {
            float pos = -(s_wred[0] + s_wred[1] + s_wred[2] + s_wred[3]);
            float neg = -negp[0];
            d_out[0] = (pos + neg) / fmaxf(800.0f, (float)R);
        }
    }
}

// ---------------------------------------------------------------------------
extern "C" void kernel_launch(void* const* d_in, const int* in_sizes, int n_in,
                              void* d_out, int out_size, void* d_ws, size_t ws_size,
                              hipStream_t stream) {
    const float* rois   = (const float*)d_in[0];
    const float* c0     = (const float*)d_in[1];
    const float* c1     = (const float*)d_in[2];
    const float* c2     = (const float*)d_in[3];
    const float* c3     = (const float*)d_in[4];
    const float* clsnew = (const float*)d_in[5];
    const int*   imlab  = (const int*)d_in[6];
    int R = in_sizes[0] / 4;

    float* ws  = (float*)d_ws;
    float* out = (float*)d_out;

    void* args[] = { (void*)&rois, (void*)&c0, (void*)&c1, (void*)&c2, (void*)&c3,
                     (void*)&clsnew, (void*)&imlab, (void*)&ws, (void*)&out, (void*)&R };
    hipLaunchCooperativeKernel((const void*)fused_kernel, dim3(GRID), dim3(TPB),
                               args, 0, stream);
}

// Round 3
// 153.826 us; speedup vs baseline: 2.0954x; 2.0954x over previous
//
#include <hip/hip_runtime.h>
#include <cfloat>
#include <climits>
#include <math.h>

#define NSTREAM 4
#define NCLS    20
#define NGT     (NSTREAM * NCLS)     // 80
#define TPB     256
#define TPB_B   320
#define ROWS_PER_CHUNK 256
#define CHUNKS  2
#define ROWS_PER_BLOCK (ROWS_PER_CHUNK * CHUNKS)   // 512
#define PADW    21                   // padded row stride in words (21 coprime 32)

// Workspace layout (float offsets). xblk <= 200 for R=100000.
#define WS_PV    0                   // [80][xblk]
#define WS_PI    16000               // [80][xblk] (int)
#define WS_GTB   32000               // [80][4]
#define WS_GTS   32320               // [80]
#define WS_VALID 32400               // [80] (int)
#define WS_SUMS  32480               // [80]
#define WS_CNTS  32560               // [80]
#define WS_NEG   32640               // [1]
#define WS_NV    32641               // [1] (int)
#define WS_GLIST 32642               // [80] (int)

// ---------------------------------------------------------------------------
// Kernel A: per-(stream,class) argmax partials with LDS-staged coalesced reads.
// grid = (xblk, 4). Each block: 2 chunks x 256 contiguous rows.
// ---------------------------------------------------------------------------
__global__ __launch_bounds__(TPB) void argmax_kernel(
    const float* __restrict__ c0, const float* __restrict__ c1,
    const float* __restrict__ c2, const float* __restrict__ c3,
    float* __restrict__ pv, int* __restrict__ pi, int R, int xblk)
{
    __shared__ float stage[ROWS_PER_CHUNK * PADW];   // 21504 B
    __shared__ float sv[NCLS][4];
    __shared__ int   si[NCLS][4];

    const int s   = blockIdx.y;
    const int xb  = blockIdx.x;
    const float* cls = (s == 0) ? c0 : (s == 1) ? c1 : (s == 2) ? c2 : c3;
    const int tid  = threadIdx.x;
    const int lane = tid & 63;
    const int wv   = tid >> 6;

    float bv[NCLS];
    int   bi_[NCLS];
#pragma unroll
    for (int c = 0; c < NCLS; ++c) { bv[c] = -FLT_MAX; bi_[c] = INT_MAX; }

    const int r0b = xb * ROWS_PER_BLOCK;
    for (int k = 0; k < CHUNKS; ++k) {
        const int r0 = r0b + k * ROWS_PER_CHUNK;
        int rows = R - r0;
        if (rows > ROWS_PER_CHUNK) rows = ROWS_PER_CHUNK;

        if (rows > 0) {
            const float4* src = reinterpret_cast<const float4*>(cls + (size_t)r0 * NCLS);
            const int nf4 = rows * (NCLS / 4);       // rows*5 float4s
#pragma unroll
            for (int j = 0; j < 5; ++j) {
                const int f = tid + j * TPB;
                if (f < nf4) {
                    float4 v = src[f];               // fully coalesced
                    const int w   = 4 * f;
                    const int row = w / NCLS;        // magic-mul div
                    const int col = w - row * NCLS;  // in {0,4,8,12,16}
                    float* d = &stage[row * PADW + col];
                    d[0] = v.x; d[1] = v.y; d[2] = v.z; d[3] = v.w;
                }
            }
        }
        __syncthreads();
        if (rows > 0 && tid < rows) {
            const int gidx = r0 + tid;
            const float* rowp = &stage[tid * PADW];  // conflict-free (21 coprime 32)
#pragma unroll
            for (int c = 0; c < NCLS; ++c) {
                float v = rowp[c];
                if (v > bv[c]) { bv[c] = v; bi_[c] = gidx; }  // strict > keeps earlier row
            }
        }
        __syncthreads();
    }

    // wave shuffle reduction, first-occurrence tie-break
#pragma unroll
    for (int off = 32; off > 0; off >>= 1) {
#pragma unroll
        for (int c = 0; c < NCLS; ++c) {
            float ov = __shfl_down(bv[c], off);
            int   oi = __shfl_down(bi_[c], off);
            if (ov > bv[c] || (ov == bv[c] && oi < bi_[c])) { bv[c] = ov; bi_[c] = oi; }
        }
    }
    if (lane == 0) {
#pragma unroll
        for (int c = 0; c < NCLS; ++c) { sv[c][wv] = bv[c]; si[c][wv] = bi_[c]; }
    }
    __syncthreads();
    if (tid < NCLS) {
        float best = sv[tid][0]; int bidx = si[tid][0];
#pragma unroll
        for (int w = 1; w < 4; ++w) {
            float v = sv[tid][w]; int i = si[tid][w];
            if (v > best || (v == best && i < bidx)) { best = v; bidx = i; }
        }
        const int p = s * NCLS + tid;               // pair index
        pv[(size_t)p * xblk + xb] = best;
        pi[(size_t)p * xblk + xb] = bidx;
    }
}

// ---------------------------------------------------------------------------
// Kernel B: final argmax reduce (4x80 threads) + instance selector +
// valid-gt compaction + bin zero-init. Single block of 320 threads.
// ---------------------------------------------------------------------------
__global__ __launch_bounds__(TPB_B) void select_kernel(
    const float* __restrict__ rois,
    const int* __restrict__ imlab,
    float* ws, float* __restrict__ d_out, int xblk)
{
    const float* pv   = ws + WS_PV;
    const int*   pi   = (const int*)(ws + WS_PI);
    float* gtb   = ws + WS_GTB;
    float* gts   = ws + WS_GTS;
    int*   valid = (int*)(ws + WS_VALID);
    float* sums  = ws + WS_SUMS;
    float* cnts  = ws + WS_CNTS;
    int*   nvp   = (int*)(ws + WS_NV);
    int*   glist = (int*)(ws + WS_GLIST);

    const int tid = threadIdx.x;
    __shared__ float s_pv4[4][NGT];
    __shared__ int   s_pi4[4][NGT];
    __shared__ float s_box[NGT][4];

    {   // parallel partial reduce: 4 threads per pair
        const int q = tid / NGT;         // 0..3
        const int p = tid % NGT;
        const int chunk = (xblk + 3) >> 2;
        const int b0 = q * chunk;
        int b1 = b0 + chunk; if (b1 > xblk) b1 = xblk;
        float best = -FLT_MAX; int bidx = INT_MAX;
        for (int b = b0; b < b1; ++b) {
            float v = pv[(size_t)p * xblk + b];
            int   i = pi[(size_t)p * xblk + b];
            if (v > best || (v == best && i < bidx)) { best = v; bidx = i; }
        }
        s_pv4[q][p] = best; s_pi4[q][p] = bidx;
    }
    __syncthreads();

    if (tid < NGT) {
        float best = s_pv4[0][tid]; int bidx = s_pi4[0][tid];
#pragma unroll
        for (int q = 1; q < 4; ++q) {
            float v = s_pv4[q][tid]; int i = s_pi4[q][tid];
            if (v > best || (v == best && i < bidx)) { best = v; bidx = i; }
        }
        const int st = tid / NCLS;
        const int c  = tid % NCLS;
        const int g  = c * NSTREAM + st;             // class-major gt index
        float4 box = reinterpret_cast<const float4*>(rois)[bidx];
        s_box[g][0] = box.x; s_box[g][1] = box.y;
        s_box[g][2] = box.z; s_box[g][3] = box.w;
        gtb[g * 4 + 0] = box.x; gtb[g * 4 + 1] = box.y;
        gtb[g * 4 + 2] = box.z; gtb[g * 4 + 3] = box.w;
        gts[g] = best;
        d_out[1 + g * 4 + 0] = box.x; d_out[1 + g * 4 + 1] = box.y;
        d_out[1 + g * 4 + 2] = box.z; d_out[1 + g * 4 + 3] = box.w;
        d_out[1 + NGT * 4 + g] = best;
        sums[g] = 0.0f; cnts[g] = 0.0f;
    }
    if (tid == 0) ws[WS_NEG] = 0.0f;
    __syncthreads();

    if (tid < NCLS) {
        const int c = tid;
        const bool present = imlab[c] > 0;
        float bx[NSTREAM][4], area[NSTREAM];
#pragma unroll
        for (int s = 0; s < NSTREAM; ++s) {
#pragma unroll
            for (int k = 0; k < 4; ++k) bx[s][k] = s_box[c * NSTREAM + s][k];
            area[s] = (bx[s][2] - bx[s][0] + 1.0f) * (bx[s][3] - bx[s][1] + 1.0f);
        }
        bool active[NSTREAM], sel[NSTREAM];
#pragma unroll
        for (int s = 0; s < NSTREAM; ++s) { active[s] = present; sel[s] = false; }

        for (int it = 0; it < NSTREAM; ++it) {
            int m = 0; float best = -FLT_MAX;
#pragma unroll
            for (int s = 0; s < NSTREAM; ++s) {
                float v = active[s] ? area[s] : -FLT_MAX;
                if (v > best) { best = v; m = s; }
            }
            const float bmx1 = bx[m][0], bmy1 = bx[m][1];
            const float bmx2 = bx[m][2], bmy2 = bx[m][3];
            const float am = area[m];
            bool nact[NSTREAM];
#pragma unroll
            for (int s = 0; s < NSTREAM; ++s) {
                float x1 = fmaxf(bx[s][0], bmx1), y1 = fmaxf(bx[s][1], bmy1);
                float x2 = fminf(bx[s][2], bmx2), y2 = fminf(bx[s][3], bmy2);
                float iw = fmaxf(x2 - x1 + 1.0f, 0.0f), ih = fmaxf(y2 - y1 + 1.0f, 0.0f);
                float inter = iw * ih;
                float iou = inter / (area[s] + am - inter);
                bool enclosed = (bx[s][0] > bmx1) && (bx[s][1] > bmy1) &&
                                (bx[s][2] < bmx2) && (bx[s][3] < bmy2);
                bool pick = active[s] && (s == m);
                bool keep = active[s] && (iou < 0.1f) && (!enclosed);
                sel[s] = sel[s] || pick || keep;
                nact[s] = active[s] && !((iou > 0.3f) || enclosed || keep);
            }
#pragma unroll
            for (int s = 0; s < NSTREAM; ++s) active[s] = nact[s];
        }
#pragma unroll
        for (int s = 0; s < NSTREAM; ++s) {
            const int g = c * NSTREAM + s;
            valid[g] = sel[s] ? 1 : 0;
            d_out[1 + NGT * 4 + NGT + g] = sel[s] ? 1.0f : 0.0f;
        }
    }
    __syncthreads();

    if (tid == 0) {     // compact valid gt list (ascending g preserves tie-break)
        int nv = 0;
        for (int g = 0; g < NGT; ++g) if (valid[g]) glist[nv++] = g;
        nvp[0] = nv;
    }
}

// ---------------------------------------------------------------------------
// Kernel C: per-roi IoU argmax against compacted valid gts, LDS bins,
// one global atomic per bin per block.
// ---------------------------------------------------------------------------
__global__ __launch_bounds__(TPB) void assign_kernel(
    const float* __restrict__ rois, const float* __restrict__ clsnew,
    float* ws, int R)
{
    const float* gtb  = ws + WS_GTB;
    const float* gts  = ws + WS_GTS;
    float* sums = ws + WS_SUMS;
    float* cnts = ws + WS_CNTS;
    float* negp = ws + WS_NEG;
    const int* nvp   = (const int*)(ws + WS_NV);
    const int* glist = (const int*)(ws + WS_GLIST);

    __shared__ float4 s_gt[NGT];
    __shared__ float  s_ga[NGT];
    __shared__ float  s_gs[NGT];
    __shared__ int    s_lab[NGT];
    __shared__ int    s_gidx[NGT];
    __shared__ float  s_sum[NGT];
    __shared__ float  s_cnt[NGT];
    __shared__ float  s_neg;
    __shared__ int    s_nv;

    const int tid = threadIdx.x;
    if (tid == 0) { s_neg = 0.0f; s_nv = nvp[0]; }
    if (tid < NGT) { s_sum[tid] = 0.0f; s_cnt[tid] = 0.0f; }
    __syncthreads();
    const int nv = s_nv;
    if (tid < nv) {
        const int g = glist[tid];
        float4 b = reinterpret_cast<const float4*>(gtb)[g];
        s_gt[tid] = b;
        s_ga[tid] = (b.z - b.x + 1.0f) * (b.w - b.y + 1.0f);
        s_gs[tid] = gts[g];
        s_lab[tid] = g / NSTREAM + 1;
        s_gidx[tid] = g;
    }
    __syncthreads();

    const int r = blockIdx.x * TPB + tid;
    if (r < R) {
        float4 bb = reinterpret_cast<const float4*>(rois)[r];
        float ab = (bb.z - bb.x + 1.0f) * (bb.w - bb.y + 1.0f);
        float best = -FLT_MAX; int bestj = 0;
        for (int j = 0; j < nv; ++j) {
            float4 gt = s_gt[j];
            float x1 = fmaxf(bb.x, gt.x), y1 = fmaxf(bb.y, gt.y);
            float x2 = fminf(bb.z, gt.z), y2 = fminf(bb.w, gt.w);
            float iw = fmaxf(x2 - x1 + 1.0f, 0.0f), ih = fmaxf(y2 - y1 + 1.0f, 0.0f);
            float inter = iw * ih;
            float v = inter / (ab + s_ga[j] - inter);
            if (v > best) { best = v; bestj = j; }   // first-max tie-break
        }
        if (best >= 0.5f) {                          // fg
            const int lab = s_lab[bestj];
            float pa = clsnew[(size_t)r * (NCLS + 1) + lab];
            pa = fminf(fmaxf(pa, 1e-9f), 1.0f - 1e-9f);
            atomicAdd(&s_sum[bestj], pa);
            atomicAdd(&s_cnt[bestj], 1.0f);
        } else if (best >= 0.1f) {                   // bg with nonzero weight
            float p0 = clsnew[(size_t)r * (NCLS + 1)];
            p0 = fminf(fmaxf(p0, 1e-9f), 1.0f - 1e-9f);
            atomicAdd(&s_neg, logf(p0) * s_gs[bestj]);
        }
    }
    __syncthreads();

    if (tid < nv && s_cnt[tid] != 0.0f) {
        atomicAdd(&sums[s_gidx[tid]], s_sum[tid]);
        atomicAdd(&cnts[s_gidx[tid]], s_cnt[tid]);
    }
    if (tid == 0 && s_neg != 0.0f) atomicAdd(negp, s_neg);
}

// ---------------------------------------------------------------------------
// Kernel D: finalize loss. Single block, 128 threads.
// ---------------------------------------------------------------------------
__global__ __launch_bounds__(128) void finalize_kernel(
    float* ws, float* __restrict__ d_out, int R)
{
    const float* sums  = ws + WS_SUMS;
    const float* cnts  = ws + WS_CNTS;
    const float* gts   = ws + WS_GTS;
    const int*   valid = (const int*)(ws + WS_VALID);
    const float* negp  = ws + WS_NEG;

    __shared__ float s_wred[2];
    const int tid = threadIdx.x;
    const int lane = tid & 63;
    float t = 0.0f;
    if (tid < NGT) {
        float cnt = cnts[tid];
        if (valid[tid] && cnt > 0.0f)
            t = logf(sums[tid] / cnt) * cnt * gts[tid];
    }
#pragma unroll
    for (int off = 32; off > 0; off >>= 1) t += __shfl_down(t, off);
    if (lane == 0) s_wred[tid >> 6] = t;
    __syncthreads();
    if (tid == 0) {
        float pos = -(s_wred[0] + s_wred[1]);
        float neg = -negp[0];
        d_out[0] = (pos + neg) / fmaxf(800.0f, (float)R);
    }
}

// ---------------------------------------------------------------------------
extern "C" void kernel_launch(void* const* d_in, const int* in_sizes, int n_in,
                              void* d_out, int out_size, void* d_ws, size_t ws_size,
                              hipStream_t stream) {
    const float* rois   = (const float*)d_in[0];
    const float* c0     = (const float*)d_in[1];
    const float* c1     = (const float*)d_in[2];
    const float* c2     = (const float*)d_in[3];
    const float* c3     = (const float*)d_in[4];
    const float* clsnew = (const float*)d_in[5];
    const int*   imlab  = (const int*)d_in[6];
    const int R = in_sizes[0] / 4;

    float* ws  = (float*)d_ws;
    float* out = (float*)d_out;
    float* pv  = ws + WS_PV;
    int*   pi  = (int*)(ws + WS_PI);

    const int xblk = (R + ROWS_PER_BLOCK - 1) / ROWS_PER_BLOCK;   // 196 @ R=100000

    argmax_kernel<<<dim3(xblk, NSTREAM), TPB, 0, stream>>>(c0, c1, c2, c3, pv, pi, R, xblk);
    select_kernel<<<1, TPB_B, 0, stream>>>(rois, imlab, ws, out, xblk);
    assign_kernel<<<(R + TPB - 1) / TPB, TPB, 0, stream>>>(rois, clsnew, ws, R);
    finalize_kernel<<<1, 128, 0, stream>>>(ws, out, R);
}